// Round 5
// baseline (153.187 us; speedup 1.0000x reference)
//
#include <hip/hip_runtime.h>
#include <hip/hip_bf16.h>
#include <math.h>

// N-BEATS SeasonalityBlock, fused persistent kernel, round 5.
// - swapped-operand MFMA => b64 LDS epilogue writes / dwordx4 out stores
// - ping-pong h0/h1 (128KB LDS), raw s_barrier + lgkmcnt only (W prefetch
//   survives layer boundaries; depth-6 rotating prefetch, cross-layer)
// 256 blocks x 512 threads (8 waves, 1 block/CU); block owns 64 batch rows.

#define BATCH 16384
#define ROWS  64

typedef __bf16 bf16x8 __attribute__((ext_vector_type(8)));
typedef float  f32x4  __attribute__((ext_vector_type(4)));

__device__ __forceinline__ unsigned short f2bf(float f) {
  union { float f; unsigned u; } v; v.f = f;
  unsigned r = v.u + 0x7fff + ((v.u >> 16) & 1);   // RTNE
  return (unsigned short)(r >> 16);
}

// ---------------- prep (unchanged from round 4) ---------------------------
// Packed B layout in 16B units: unit u = (cf*KS + ks)*64 + lane holds
// W[cf*16 + (lane&15)][ks*32 + (lane>>4)*8 + e], e=0..7  (KS = K/32).
__global__ __launch_bounds__(256) void prep_kernel(
    const float* __restrict__ W1, const float* __restrict__ W2,
    const float* __restrict__ W3, const float* __restrict__ W4,
    const float* __restrict__ Wt,
    unsigned short* __restrict__ W1p, unsigned short* __restrict__ W2p,
    unsigned short* __restrict__ W3p, unsigned short* __restrict__ W4p,
    unsigned short* __restrict__ Wtp,
    unsigned short* __restrict__ basp) {
  const int t = blockIdx.x * 256 + threadIdx.x;
  if (t < 139264) {
    const float* src; unsigned short* dst; int u;
    if (t < 131072) {
      const int w = t >> 15; u = t & 32767;
      src = (w == 0) ? W1 : (w == 1) ? W2 : (w == 2) ? W3 : W4;
      dst = (w == 0) ? W1p : (w == 1) ? W2p : (w == 2) ? W3p : W4p;
    } else {
      u = t - 131072; src = Wt; dst = Wtp;
    }
    const int lane = u & 63, ks = (u >> 6) & 15, cf = u >> 10;
    const int col = cf * 16 + (lane & 15);
    const int k0  = ks * 32 + (lane >> 4) * 8;
    const float4* s = (const float4*)(src + (size_t)col * 512 + k0);
    const float4 a = s[0], b = s[1];
    uint4 o;
    o.x = f2bf(a.x) | ((unsigned)f2bf(a.y) << 16);
    o.y = f2bf(a.z) | ((unsigned)f2bf(a.w) << 16);
    o.z = f2bf(b.x) | ((unsigned)f2bf(b.y) << 16);
    o.w = f2bf(b.z) | ((unsigned)f2bf(b.w) << 16);
    ((uint4*)dst)[u] = o;
  } else if (t < 149504) {
    const int u = t - 139264;
    const int lane = u & 63, ks = (u >> 6) & 3, cf = u >> 8;
    const int col = cf * 16 + (lane & 15);
    const int r0  = ks * 32 + (lane >> 4) * 8;
    int l, L;
    if (col < 512) { l = col; L = 512; } else { l = col - 512; L = 128; }
    const float w0 = 6.283185307179586f * (float)l / (float)L;
    unsigned short e[8];
#pragma unroll
    for (int i = 0; i < 8; ++i) {
      const int r = r0 + i;
      const float ang = (float)(r >> 1) * w0;
      e[i] = f2bf((r & 1) ? sinf(ang) : cosf(ang));
    }
    uint4 o;
    o.x = e[0] | ((unsigned)e[1] << 16);
    o.y = e[2] | ((unsigned)e[3] << 16);
    o.z = e[4] | ((unsigned)e[5] << 16);
    o.w = e[6] | ((unsigned)e[7] << 16);
    ((uint4*)basp)[u] = o;
  }
}

__device__ __forceinline__ void wait_lds_and_barrier() {
  asm volatile("s_waitcnt lgkmcnt(0)" ::: "memory");
  __builtin_amdgcn_sched_barrier(0);
  __builtin_amdgcn_s_barrier();
  __builtin_amdgcn_sched_barrier(0);
}

// ---------------- one FC+ReLU layer: hout = relu(hin @ W^T + b) ----------
// PHASE = (L*16) % 6 (prefetch slot offset). PF_NEXT: prefetch next layer's
// first 5 k-steps into bv (stays in flight across the barrier).
template <int PHASE, bool PF_NEXT>
__device__ __forceinline__ void layer512(
    const unsigned short* hin, unsigned short* hout,
    const bf16x8* __restrict__ wcur, const bf16x8* __restrict__ wnext,
    const float* __restrict__ bias, bf16x8 (&bv)[6][4],
    const int wv, const int lane) {
  const int l15 = lane & 15, g = lane >> 4;
  f32x4 acc[4][4];
#pragma unroll
  for (int m = 0; m < 4; ++m)
#pragma unroll
    for (int n = 0; n < 4; ++n) acc[m][n] = (f32x4){0.f, 0.f, 0.f, 0.f};

  float4 bias4[4];
#pragma unroll
  for (int n = 0; n < 4; ++n)
    bias4[n] = *(const float4*)(bias + wv * 64 + n * 16 + g * 4);

  int rb[4], am[4];
#pragma unroll
  for (int m = 0; m < 4; ++m) {
    const int row = m * 16 + l15;
    rb[m] = row * 1024;
    am[m] = (row & 7) << 4;
  }

#pragma unroll
  for (int ks = 0; ks < 16; ++ks) {
    // prefetch global k-step (L*16 + ks + 5)
    if (ks < 11) {
#pragma unroll
      for (int n = 0; n < 4; ++n)
        bv[(PHASE + ks + 5) % 6][n] = wcur[n * 1024 + (ks + 5) * 64];
    } else if (PF_NEXT) {
#pragma unroll
      for (int n = 0; n < 4; ++n)
        bv[(PHASE + ks + 5) % 6][n] = wnext[n * 1024 + (ks - 11) * 64];
    }
    bf16x8 av[4];
    const int kb = ks * 64 + g * 16;
#pragma unroll
    for (int m = 0; m < 4; ++m)
      av[m] = *(const bf16x8*)((const char*)hin + rb[m] + (kb ^ am[m]));
    __builtin_amdgcn_s_setprio(1);
#pragma unroll
    for (int m = 0; m < 4; ++m)
#pragma unroll
      for (int n = 0; n < 4; ++n)
        acc[m][n] = __builtin_amdgcn_mfma_f32_16x16x32_bf16(
            bv[(PHASE + ks) % 6][n], av[m], acc[m][n], 0, 0, 0);
    __builtin_amdgcn_s_setprio(0);
  }

  // epilogue: lane (g,l15) holds, per (m,n): batch row m*16+l15,
  // output cols wv*64 + n*16 + g*4 + (0..3)  -> one b64 LDS write
#pragma unroll
  for (int m = 0; m < 4; ++m) {
    const int row = m * 16 + l15;
    const int sw  = (row & 7) << 4;
#pragma unroll
    for (int n = 0; n < 4; ++n) {
      const float v0 = fmaxf(acc[m][n][0] + bias4[n].x, 0.f);
      const float v1 = fmaxf(acc[m][n][1] + bias4[n].y, 0.f);
      const float v2 = fmaxf(acc[m][n][2] + bias4[n].z, 0.f);
      const float v3 = fmaxf(acc[m][n][3] + bias4[n].w, 0.f);
      uint2 o;
      o.x = f2bf(v0) | ((unsigned)f2bf(v1) << 16);
      o.y = f2bf(v2) | ((unsigned)f2bf(v3) << 16);
      const int c0 = (wv * 64 + n * 16 + g * 4) * 2;
      *(uint2*)((char*)hout + row * 1024 + (c0 ^ sw)) = o;
    }
  }
  wait_lds_and_barrier();
}

// ---------------- fused mega-kernel --------------------------------------
__global__ __launch_bounds__(512, 2) void fused_nbeats(
    const float* __restrict__ x,
    const bf16x8* __restrict__ W1p, const float* __restrict__ b1,
    const bf16x8* __restrict__ W2p, const float* __restrict__ b2,
    const bf16x8* __restrict__ W3p, const float* __restrict__ b3,
    const bf16x8* __restrict__ W4p, const float* __restrict__ b4,
    const bf16x8* __restrict__ Wtp,
    const bf16x8* __restrict__ basp,
    float* __restrict__ out) {
  __shared__ __align__(16) unsigned short h0[ROWS * 512];   // 64 KB
  __shared__ __align__(16) unsigned short h1[ROWS * 512];   // 64 KB

  const int tid  = threadIdx.x;
  const int lane = tid & 63;
  const int wv   = tid >> 6;
  const int l15  = lane & 15, g = lane >> 4;
  const int r0   = blockIdx.x * ROWS;

  const bf16x8* w1 = W1p + (size_t)wv * 4096 + lane;
  const bf16x8* w2 = W2p + (size_t)wv * 4096 + lane;
  const bf16x8* w3 = W3p + (size_t)wv * 4096 + lane;
  const bf16x8* w4 = W4p + (size_t)wv * 4096 + lane;

  bf16x8 bv[6][4];
  // initial fill: W1 k-steps 0..4 -> slots 0..4 (issued before x loads)
#pragma unroll
  for (int s = 0; s < 5; ++s)
#pragma unroll
    for (int n = 0; n < 4; ++n) bv[s][n] = w1[n * 1024 + s * 64];

  // ---- phase 0: x fp32 -> h0 bf16 (swizzled rows, 1024B stride) ----
  {
    const float4* xs = (const float4*)(x + (size_t)r0 * 512);
#pragma unroll
    for (int j = 0; j < 16; ++j) {
      const int f = tid + j * 512;          // float4 index in [64][128]
      const int row = f >> 7, c4 = f & 127;
      const float4 v = xs[f];
      uint2 o;
      o.x = f2bf(v.x) | ((unsigned)f2bf(v.y) << 16);
      o.y = f2bf(v.z) | ((unsigned)f2bf(v.w) << 16);
      *(uint2*)((char*)h0 + row * 1024 + ((c4 * 8) ^ ((row & 7) << 4))) = o;
    }
  }
  wait_lds_and_barrier();

  // ---- 4 FC+ReLU layers (ping-pong) ----
  layer512<0, true >(h0, h1, w1, w2, b1, bv, wv, lane);
  layer512<4, true >(h1, h0, w2, w3, b2, bv, wv, lane);
  layer512<2, true >(h0, h1, w3, w4, b3, bv, wv, lane);
  layer512<0, false>(h1, h0, w4, (const bf16x8*)0, b4, bv, wv, lane);

  // ---- theta = h4 @ Wt^T : wave wv -> theta cols wv*16 .. +15 ----
  {
    const bf16x8* tb = Wtp + (size_t)wv * 1024 + lane;
    bf16x8 tv[16];
#pragma unroll
    for (int s = 0; s < 16; ++s) tv[s] = tb[s * 64];

    int rb[4], am[4];
#pragma unroll
    for (int m = 0; m < 4; ++m) {
      const int row = m * 16 + l15;
      rb[m] = row * 1024;
      am[m] = (row & 7) << 4;
    }
    f32x4 tacc[4];
#pragma unroll
    for (int m = 0; m < 4; ++m) tacc[m] = (f32x4){0.f, 0.f, 0.f, 0.f};
#pragma unroll
    for (int ks = 0; ks < 16; ++ks) {
      bf16x8 av[4];
      const int kb = ks * 64 + g * 16;
#pragma unroll
      for (int m = 0; m < 4; ++m)
        av[m] = *(const bf16x8*)((const char*)h0 + rb[m] + (kb ^ am[m]));
      __builtin_amdgcn_s_setprio(1);
#pragma unroll
      for (int m = 0; m < 4; ++m)
        tacc[m] = __builtin_amdgcn_mfma_f32_16x16x32_bf16(
            tv[ks], av[m], tacc[m], 0, 0, 0);
      __builtin_amdgcn_s_setprio(0);
    }
    // basis B preload (flies during theta epilogue + barrier)
    // (declared below, loads issued here via the bb pointer)
    // theta epilogue: batch row m*16+l15, theta cols wv*16+g*4+(0..3)
#pragma unroll
    for (int m = 0; m < 4; ++m) {
      const int row = m * 16 + l15;
      const int sw  = (row & 7) << 4;
      uint2 o;
      o.x = f2bf(tacc[m][0]) | ((unsigned)f2bf(tacc[m][1]) << 16);
      o.y = f2bf(tacc[m][2]) | ((unsigned)f2bf(tacc[m][3]) << 16);
      const int c0 = (wv * 16 + g * 4) * 2;
      *(uint2*)((char*)h1 + row * 256 + (c0 ^ sw)) = o;
    }
  }
  wait_lds_and_barrier();

  // ---- backcast/forecast: out = theta @ basT^T (wave wv -> 80 cols) ----
  {
    const bf16x8* bb = basp + (size_t)wv * 1280 + lane;   // cf = wv*5+n, KS=4
    bf16x8 bvv[5][4];
#pragma unroll
    for (int n = 0; n < 5; ++n)
#pragma unroll
      for (int ks = 0; ks < 4; ++ks) bvv[n][ks] = bb[n * 256 + ks * 64];

    f32x4 facc[4][5];
#pragma unroll
    for (int m = 0; m < 4; ++m)
#pragma unroll
      for (int n = 0; n < 5; ++n) facc[m][n] = (f32x4){0.f, 0.f, 0.f, 0.f};
    int rb2[4], am2[4];
#pragma unroll
    for (int m = 0; m < 4; ++m) {
      const int row = m * 16 + l15;
      rb2[m] = row * 256;
      am2[m] = (row & 7) << 4;
    }
#pragma unroll
    for (int ks = 0; ks < 4; ++ks) {
      bf16x8 av[4];
      const int kb = ks * 64 + g * 16;
#pragma unroll
      for (int m = 0; m < 4; ++m)
        av[m] = *(const bf16x8*)((const char*)h1 + rb2[m] + (kb ^ am2[m]));
      __builtin_amdgcn_s_setprio(1);
#pragma unroll
      for (int n = 0; n < 5; ++n)
#pragma unroll
        for (int m = 0; m < 4; ++m)
          facc[m][n] = __builtin_amdgcn_mfma_f32_16x16x32_bf16(
              bvv[n][ks], av[m], facc[m][n], 0, 0, 0);
      __builtin_amdgcn_s_setprio(0);
    }
    // store: lane (g,l15), frag (m,n): row r0+m*16+l15,
    // cols wv*80+n*16+g*4+(0..3) -> one dwordx4
#pragma unroll
    for (int n = 0; n < 5; ++n) {
      const int c0 = wv * 80 + n * 16 + g * 4;
#pragma unroll
      for (int m = 0; m < 4; ++m) {
        const int row = r0 + m * 16 + l15;
        float4 o = make_float4(facc[m][n][0], facc[m][n][1],
                               facc[m][n][2], facc[m][n][3]);
        if (c0 < 512)
          *(float4*)(out + (size_t)row * 512 + c0) = o;
        else
          *(float4*)(out + (size_t)BATCH * 512 + (size_t)row * 128 + (c0 - 512)) = o;
      }
    }
  }
}

// ---------------- launch --------------------------------------------------
extern "C" void kernel_launch(void* const* d_in, const int* in_sizes, int n_in,
                              void* d_out, int out_size, void* d_ws, size_t ws_size,
                              hipStream_t stream) {
  const float* x  = (const float*)d_in[0];
  const float* W1 = (const float*)d_in[1];
  const float* b1 = (const float*)d_in[2];
  const float* W2 = (const float*)d_in[3];
  const float* b2 = (const float*)d_in[4];
  const float* W3 = (const float*)d_in[5];
  const float* b3 = (const float*)d_in[6];
  const float* W4 = (const float*)d_in[7];
  const float* b4 = (const float*)d_in[8];
  const float* Wt = (const float*)d_in[9];

  unsigned short* ws  = (unsigned short*)d_ws;
  unsigned short* W1p = ws;                       // 262144 elems each
  unsigned short* W2p = ws + 262144;
  unsigned short* W3p = ws + 524288;
  unsigned short* W4p = ws + 786432;
  unsigned short* Wtp = ws + 1048576;             // 65536
  unsigned short* basp = ws + 1114112;            // 640*128 = 81920

  prep_kernel<<<584, 256, 0, stream>>>(W1, W2, W3, W4, Wt,
                                       W1p, W2p, W3p, W4p, Wtp, basp);
  fused_nbeats<<<BATCH / ROWS, 512, 0, stream>>>(
      x, (const bf16x8*)W1p, b1, (const bf16x8*)W2p, b2,
      (const bf16x8*)W3p, b3, (const bf16x8*)W4p, b4,
      (const bf16x8*)Wtp, (const bf16x8*)basp, (float*)d_out);
}

// Round 6
// 140.539 us; speedup vs baseline: 1.0900x; 1.0900x over previous
//
#include <hip/hip_runtime.h>
#include <hip/hip_bf16.h>
#include <math.h>

// N-BEATS SeasonalityBlock, fused persistent kernel, round 6.
// Round-5 structure (swapped-operand MFMA, b64 epilogues, ping-pong h0/h1,
// raw s_barrier + lgkmcnt-only waits, cross-layer W prefetch) with reduced
// register pressure: depth-3 W prefetch, rolling theta/basis B-frags,
// bias loads in epilogue. Goal: eliminate the scratch spills seen in R5
// (FETCH 26->44MB, WRITE 50->80MB were spill traffic).
// 256 blocks x 512 threads (8 waves, 1 block/CU); block owns 64 batch rows.

#define BATCH 16384
#define ROWS  64

typedef __bf16 bf16x8 __attribute__((ext_vector_type(8)));
typedef float  f32x4  __attribute__((ext_vector_type(4)));

__device__ __forceinline__ unsigned short f2bf(float f) {
  union { float f; unsigned u; } v; v.f = f;
  unsigned r = v.u + 0x7fff + ((v.u >> 16) & 1);   // RTNE
  return (unsigned short)(r >> 16);
}

// ---------------- prep ----------------------------------------------------
// Packed B layout in 16B units: unit u = (cf*KS + ks)*64 + lane holds
// W[cf*16 + (lane&15)][ks*32 + (lane>>4)*8 + e], e=0..7  (KS = K/32).
__global__ __launch_bounds__(256) void prep_kernel(
    const float* __restrict__ W1, const float* __restrict__ W2,
    const float* __restrict__ W3, const float* __restrict__ W4,
    const float* __restrict__ Wt,
    unsigned short* __restrict__ W1p, unsigned short* __restrict__ W2p,
    unsigned short* __restrict__ W3p, unsigned short* __restrict__ W4p,
    unsigned short* __restrict__ Wtp,
    unsigned short* __restrict__ basp) {
  const int t = blockIdx.x * 256 + threadIdx.x;
  if (t < 139264) {
    const float* src; unsigned short* dst; int u;
    if (t < 131072) {
      const int w = t >> 15; u = t & 32767;
      src = (w == 0) ? W1 : (w == 1) ? W2 : (w == 2) ? W3 : W4;
      dst = (w == 0) ? W1p : (w == 1) ? W2p : (w == 2) ? W3p : W4p;
    } else {
      u = t - 131072; src = Wt; dst = Wtp;
    }
    const int lane = u & 63, ks = (u >> 6) & 15, cf = u >> 10;
    const int col = cf * 16 + (lane & 15);
    const int k0  = ks * 32 + (lane >> 4) * 8;
    const float4* s = (const float4*)(src + (size_t)col * 512 + k0);
    const float4 a = s[0], b = s[1];
    uint4 o;
    o.x = f2bf(a.x) | ((unsigned)f2bf(a.y) << 16);
    o.y = f2bf(a.z) | ((unsigned)f2bf(a.w) << 16);
    o.z = f2bf(b.x) | ((unsigned)f2bf(b.y) << 16);
    o.w = f2bf(b.z) | ((unsigned)f2bf(b.w) << 16);
    ((uint4*)dst)[u] = o;
  } else if (t < 149504) {
    const int u = t - 139264;
    const int lane = u & 63, ks = (u >> 6) & 3, cf = u >> 8;
    const int col = cf * 16 + (lane & 15);
    const int r0  = ks * 32 + (lane >> 4) * 8;
    int l, L;
    if (col < 512) { l = col; L = 512; } else { l = col - 512; L = 128; }
    const float w0 = 6.283185307179586f * (float)l / (float)L;
    unsigned short e[8];
#pragma unroll
    for (int i = 0; i < 8; ++i) {
      const int r = r0 + i;
      const float ang = (float)(r >> 1) * w0;
      e[i] = f2bf((r & 1) ? sinf(ang) : cosf(ang));
    }
    uint4 o;
    o.x = e[0] | ((unsigned)e[1] << 16);
    o.y = e[2] | ((unsigned)e[3] << 16);
    o.z = e[4] | ((unsigned)e[5] << 16);
    o.w = e[6] | ((unsigned)e[7] << 16);
    ((uint4*)basp)[u] = o;
  }
}

__device__ __forceinline__ void wait_lds_and_barrier() {
  asm volatile("s_waitcnt lgkmcnt(0)" ::: "memory");
  __builtin_amdgcn_sched_barrier(0);
  __builtin_amdgcn_s_barrier();
  __builtin_amdgcn_sched_barrier(0);
}

// ---------------- one FC+ReLU layer: hout = relu(hin @ W^T + b) ----------
// Depth-3 rotating prefetch, issue distance 2 k-steps. PHASE = (L*16) % 3.
// PF_NEXT: prefetch next layer's k-steps 0,1 at ks=14,15 (slots line up:
// PHASE_next = (PHASE+1)%3 and 16 == 1 mod 3).
template <int PHASE, bool PF_NEXT>
__device__ __forceinline__ void layer512(
    const unsigned short* hin, unsigned short* hout,
    const bf16x8* __restrict__ wcur, const bf16x8* __restrict__ wnext,
    const float* __restrict__ bias, bf16x8 (&bv)[3][4],
    const int wv, const int lane) {
  const int l15 = lane & 15, g = lane >> 4;
  f32x4 acc[4][4];
#pragma unroll
  for (int m = 0; m < 4; ++m)
#pragma unroll
    for (int n = 0; n < 4; ++n) acc[m][n] = (f32x4){0.f, 0.f, 0.f, 0.f};

  int rb[4], am[4];
#pragma unroll
  for (int m = 0; m < 4; ++m) {
    const int row = m * 16 + l15;
    rb[m] = row * 1024;
    am[m] = (row & 7) << 4;
  }

#pragma unroll
  for (int ks = 0; ks < 16; ++ks) {
    if (ks < 14) {
#pragma unroll
      for (int n = 0; n < 4; ++n)
        bv[(PHASE + ks + 2) % 3][n] = wcur[n * 1024 + (ks + 2) * 64];
    } else if (PF_NEXT) {
#pragma unroll
      for (int n = 0; n < 4; ++n)
        bv[(PHASE + ks + 2) % 3][n] = wnext[n * 1024 + (ks - 14) * 64];
    }
    bf16x8 av[4];
    const int kb = ks * 64 + g * 16;
#pragma unroll
    for (int m = 0; m < 4; ++m)
      av[m] = *(const bf16x8*)((const char*)hin + rb[m] + (kb ^ am[m]));
    __builtin_amdgcn_s_setprio(1);
#pragma unroll
    for (int m = 0; m < 4; ++m)
#pragma unroll
      for (int n = 0; n < 4; ++n)
        acc[m][n] = __builtin_amdgcn_mfma_f32_16x16x32_bf16(
            bv[(PHASE + ks) % 3][n], av[m], acc[m][n], 0, 0, 0);
    __builtin_amdgcn_s_setprio(0);
  }

  // epilogue: lane (g,l15), frag (m,n): batch row m*16+l15,
  // output cols wv*64 + n*16 + g*4 + (0..3)  -> one b64 LDS write
  float4 bias4[4];
#pragma unroll
  for (int n = 0; n < 4; ++n)
    bias4[n] = *(const float4*)(bias + wv * 64 + n * 16 + g * 4);
#pragma unroll
  for (int m = 0; m < 4; ++m) {
    const int row = m * 16 + l15;
    const int sw  = (row & 7) << 4;
#pragma unroll
    for (int n = 0; n < 4; ++n) {
      const float v0 = fmaxf(acc[m][n][0] + bias4[n].x, 0.f);
      const float v1 = fmaxf(acc[m][n][1] + bias4[n].y, 0.f);
      const float v2 = fmaxf(acc[m][n][2] + bias4[n].z, 0.f);
      const float v3 = fmaxf(acc[m][n][3] + bias4[n].w, 0.f);
      uint2 o;
      o.x = f2bf(v0) | ((unsigned)f2bf(v1) << 16);
      o.y = f2bf(v2) | ((unsigned)f2bf(v3) << 16);
      const int c0 = (wv * 64 + n * 16 + g * 4) * 2;
      *(uint2*)((char*)hout + row * 1024 + (c0 ^ sw)) = o;
    }
  }
  wait_lds_and_barrier();
}

// ---------------- fused mega-kernel --------------------------------------
__global__ __launch_bounds__(512, 2) void fused_nbeats(
    const float* __restrict__ x,
    const bf16x8* __restrict__ W1p, const float* __restrict__ b1,
    const bf16x8* __restrict__ W2p, const float* __restrict__ b2,
    const bf16x8* __restrict__ W3p, const float* __restrict__ b3,
    const bf16x8* __restrict__ W4p, const float* __restrict__ b4,
    const bf16x8* __restrict__ Wtp,
    const bf16x8* __restrict__ basp,
    float* __restrict__ out) {
  __shared__ __align__(16) unsigned short h0[ROWS * 512];   // 64 KB
  __shared__ __align__(16) unsigned short h1[ROWS * 512];   // 64 KB

  const int tid  = threadIdx.x;
  const int lane = tid & 63;
  const int wv   = tid >> 6;
  const int l15  = lane & 15, g = lane >> 4;
  const int r0   = blockIdx.x * ROWS;

  const bf16x8* w1 = W1p + (size_t)wv * 4096 + lane;
  const bf16x8* w2 = W2p + (size_t)wv * 4096 + lane;
  const bf16x8* w3 = W3p + (size_t)wv * 4096 + lane;
  const bf16x8* w4 = W4p + (size_t)wv * 4096 + lane;

  bf16x8 bv[3][4];
  // initial fill: W1 k-steps 0,1 -> slots 0,1 (issued before x loads)
#pragma unroll
  for (int s = 0; s < 2; ++s)
#pragma unroll
    for (int n = 0; n < 4; ++n) bv[s][n] = w1[n * 1024 + s * 64];

  // ---- phase 0: x fp32 -> h0 bf16 (swizzled rows, 1024B stride) ----
  {
    const float4* xs = (const float4*)(x + (size_t)r0 * 512);
#pragma unroll
    for (int j = 0; j < 16; ++j) {
      const int f = tid + j * 512;          // float4 index in [64][128]
      const int row = f >> 7, c4 = f & 127;
      const float4 v = xs[f];
      uint2 o;
      o.x = f2bf(v.x) | ((unsigned)f2bf(v.y) << 16);
      o.y = f2bf(v.z) | ((unsigned)f2bf(v.w) << 16);
      *(uint2*)((char*)h0 + row * 1024 + ((c4 * 8) ^ ((row & 7) << 4))) = o;
    }
  }
  wait_lds_and_barrier();

  // ---- 4 FC+ReLU layers (ping-pong); PHASE = (L*16)%3 ----
  layer512<0, true >(h0, h1, w1, w2, b1, bv, wv, lane);
  layer512<1, true >(h1, h0, w2, w3, b2, bv, wv, lane);
  layer512<2, true >(h0, h1, w3, w4, b3, bv, wv, lane);
  layer512<0, false>(h1, h0, w4, (const bf16x8*)0, b4, bv, wv, lane);

  // ---- theta = h4 @ Wt^T : wave wv -> theta cols wv*16 .. +15 ----
  {
    const bf16x8* tb = Wtp + (size_t)wv * 1024 + lane;
    bf16x8 tv[4];                          // rolling depth-4
#pragma unroll
    for (int s = 0; s < 3; ++s) tv[s] = tb[s * 64];

    int rb[4], am[4];
#pragma unroll
    for (int m = 0; m < 4; ++m) {
      const int row = m * 16 + l15;
      rb[m] = row * 1024;
      am[m] = (row & 7) << 4;
    }
    f32x4 tacc[4];
#pragma unroll
    for (int m = 0; m < 4; ++m) tacc[m] = (f32x4){0.f, 0.f, 0.f, 0.f};
#pragma unroll
    for (int ks = 0; ks < 16; ++ks) {
      if (ks < 13) tv[(ks + 3) & 3] = tb[(ks + 3) * 64];
      bf16x8 av[4];
      const int kb = ks * 64 + g * 16;
#pragma unroll
      for (int m = 0; m < 4; ++m)
        av[m] = *(const bf16x8*)((const char*)h0 + rb[m] + (kb ^ am[m]));
      __builtin_amdgcn_s_setprio(1);
#pragma unroll
      for (int m = 0; m < 4; ++m)
        tacc[m] = __builtin_amdgcn_mfma_f32_16x16x32_bf16(
            tv[ks & 3], av[m], tacc[m], 0, 0, 0);
      __builtin_amdgcn_s_setprio(0);
    }
    // theta epilogue: batch row m*16+l15, theta cols wv*16+g*4+(0..3)
#pragma unroll
    for (int m = 0; m < 4; ++m) {
      const int row = m * 16 + l15;
      const int sw  = (row & 7) << 4;
      uint2 o;
      o.x = f2bf(tacc[m][0]) | ((unsigned)f2bf(tacc[m][1]) << 16);
      o.y = f2bf(tacc[m][2]) | ((unsigned)f2bf(tacc[m][3]) << 16);
      const int c0 = (wv * 16 + g * 4) * 2;
      *(uint2*)((char*)h1 + row * 256 + (c0 ^ sw)) = o;
    }
  }
  wait_lds_and_barrier();

  // ---- backcast/forecast: out = theta @ basT^T (wave wv -> 80 cols) ----
  {
    const bf16x8* bb = basp + (size_t)wv * 1280 + lane;   // cf = wv*5+n, KS=4
    bf16x8 bvv[2][5];                      // rolling depth-2
#pragma unroll
    for (int n = 0; n < 5; ++n) bvv[0][n] = bb[n * 256];

    f32x4 facc[4][5];
#pragma unroll
    for (int m = 0; m < 4; ++m)
#pragma unroll
      for (int n = 0; n < 5; ++n) facc[m][n] = (f32x4){0.f, 0.f, 0.f, 0.f};
    int rb2[4], am2[4];
#pragma unroll
    for (int m = 0; m < 4; ++m) {
      const int row = m * 16 + l15;
      rb2[m] = row * 256;
      am2[m] = (row & 7) << 4;
    }
#pragma unroll
    for (int ks = 0; ks < 4; ++ks) {
      if (ks < 3) {
#pragma unroll
        for (int n = 0; n < 5; ++n) bvv[(ks + 1) & 1][n] = bb[n * 256 + (ks + 1) * 64];
      }
      bf16x8 av[4];
      const int kb = ks * 64 + g * 16;
#pragma unroll
      for (int m = 0; m < 4; ++m)
        av[m] = *(const bf16x8*)((const char*)h1 + rb2[m] + (kb ^ am2[m]));
      __builtin_amdgcn_s_setprio(1);
#pragma unroll
      for (int n = 0; n < 5; ++n)
#pragma unroll
        for (int m = 0; m < 4; ++m)
          facc[m][n] = __builtin_amdgcn_mfma_f32_16x16x32_bf16(
              bvv[ks & 1][n], av[m], facc[m][n], 0, 0, 0);
      __builtin_amdgcn_s_setprio(0);
    }
    // store: lane (g,l15), frag (m,n): row r0+m*16+l15,
    // cols wv*80+n*16+g*4+(0..3) -> one dwordx4
#pragma unroll
    for (int n = 0; n < 5; ++n) {
      const int c0 = wv * 80 + n * 16 + g * 4;
#pragma unroll
      for (int m = 0; m < 4; ++m) {
        const int row = r0 + m * 16 + l15;
        float4 o = make_float4(facc[m][n][0], facc[m][n][1],
                               facc[m][n][2], facc[m][n][3]);
        if (c0 < 512)
          *(float4*)(out + (size_t)row * 512 + c0) = o;
        else
          *(float4*)(out + (size_t)BATCH * 512 + (size_t)row * 128 + (c0 - 512)) = o;
      }
    }
  }
}

// ---------------- launch --------------------------------------------------
extern "C" void kernel_launch(void* const* d_in, const int* in_sizes, int n_in,
                              void* d_out, int out_size, void* d_ws, size_t ws_size,
                              hipStream_t stream) {
  const float* x  = (const float*)d_in[0];
  const float* W1 = (const float*)d_in[1];
  const float* b1 = (const float*)d_in[2];
  const float* W2 = (const float*)d_in[3];
  const float* b2 = (const float*)d_in[4];
  const float* W3 = (const float*)d_in[5];
  const float* b3 = (const float*)d_in[6];
  const float* W4 = (const float*)d_in[7];
  const float* b4 = (const float*)d_in[8];
  const float* Wt = (const float*)d_in[9];

  unsigned short* ws  = (unsigned short*)d_ws;
  unsigned short* W1p = ws;                       // 262144 elems each
  unsigned short* W2p = ws + 262144;
  unsigned short* W3p = ws + 524288;
  unsigned short* W4p = ws + 786432;
  unsigned short* Wtp = ws + 1048576;             // 65536
  unsigned short* basp = ws + 1114112;            // 640*128 = 81920

  prep_kernel<<<584, 256, 0, stream>>>(W1, W2, W3, W4, Wt,
                                       W1p, W2p, W3p, W4p, Wtp, basp);
  fused_nbeats<<<BATCH / ROWS, 512, 0, stream>>>(
      x, (const bf16x8*)W1p, b1, (const bf16x8*)W2p, b2,
      (const bf16x8*)W3p, b3, (const bf16x8*)W4p, b4,
      (const bf16x8*)Wtp, (const bf16x8*)basp, (float*)d_out);
}